// Round 5
// baseline (2013.343 us; speedup 1.0000x reference)
//
#include <hip/hip_runtime.h>

// LSTM (B=512, T=1024, I=64, H=128) + FC(128->256->1).
// v6: MFMA rewrite. v5's fp32-vector family is co-bound on VALU issue
// (~2265 cy/step/CU) and LDS b128 return (~2330 cy) -> ~1100 us floor.
// Move the per-step GEMM [512 gates x 192] @ [192 x N] to matrix cores via
// bf16x3 split (w=wh+wl, z=zh+zl; wh*zh + wh*zl + wl*zh; err ~2^-18/term).
// N=16 batch rows/block -> 32 blocks x 512 threads (8 waves, 2/SIMD).
// Wave w owns M-tiles {w, w+8, w+16, w+24} = the 4 gate classes (i,f,g,o)
// of units 16w..16w+15. C-layout (m89-verified: col=lane&15=batch row,
// row=(lane>>4)*4+reg=gate-in-tile) makes the whole c/h update LANE-LOCAL:
// lane owns 4 units x 1 row x all 4 classes -> no fold, no gbuf.
// Weights as pre-split bf16 A-fragments in regs/AGPRs (192 regs, unified
// file). z=[x(64)|h(128)] in LDS as bf16 hi+lo, double-buffered, ONE
// barrier/step. x(t+1) prefetched from global each step.

#define T_STEPS 1024
#define ISZ 64
#define HSZ 128
#define ROWS 16     // batch rows per block (= MFMA N)
#define NTH 512
#define NBLK 32
#define ZP 200      // shorts per z row (192 + 8 pad -> 400B stride)

typedef __attribute__((ext_vector_type(8))) short bf16x8;   // 8 bf16 (4 VGPR)
typedef __attribute__((ext_vector_type(4))) float f32x4;

__device__ __forceinline__ unsigned short bf16_rn(float f) {
    unsigned u = __float_as_uint(f);
    return (unsigned short)((u + 0x7FFFu + ((u >> 16) & 1u)) >> 16);
}
__device__ __forceinline__ float bf16_f(unsigned short h) {
    return __uint_as_float(((unsigned)h) << 16);
}
__device__ __forceinline__ float sigm(float s) {
    // 1/(1+e^-s): inf-safe (e^inf -> rcp(inf)=0; e^0 path exact)
    return __builtin_amdgcn_rcpf(1.0f + __expf(-s));
}
__device__ __forceinline__ float tanh_(float s) {
    // 1 - 2/(e^2s + 1): inf-safe at both ends
    return fmaf(-2.0f, __builtin_amdgcn_rcpf(__expf(2.0f * s) + 1.0f), 1.0f);
}

__global__ __launch_bounds__(NTH, 2)  // 8 waves/block, 2 waves/EU -> 256 combined regs
void lstm_fused_kernel(const float* __restrict__ x,
                       const float* __restrict__ W_ih,
                       const float* __restrict__ W_hh,
                       const float* __restrict__ b_ih,
                       const float* __restrict__ b_hh,
                       const float* __restrict__ W1,
                       const float* __restrict__ b1,
                       const float* __restrict__ W2,
                       const float* __restrict__ b2,
                       float* __restrict__ out)
{
    __shared__ __align__(16) short zH[2][ROWS][ZP];   // z hi-part, [buf][row][k]
    __shared__ __align__(16) short zL[2][ROWS][ZP];   // z lo-part
    __shared__ __align__(16) float hbuf[ROWS][132];   // final-step h (fp32) for FC
    __shared__ float red[ROWS][4];

    const int tid  = threadIdx.x;
    const int b0   = blockIdx.x * ROWS;
    const int lane = tid & 63;
    const int wv   = tid >> 6;        // wave 0..7 = class-group (units 16wv..16wv+15)
    const int n    = lane & 15;       // batch row (B/C n-col; also A m-row)
    const int qrt  = lane >> 4;       // 0..3
    const int u0   = 16 * wv + 4 * qrt;  // first hidden unit this lane owns (C layout)

    // ---- A fragments: rows of [W_ih | W_hh], bf16 hi/lo split, in regs/AGPRs ----
    // A-frag layout (16x16x32): lane holds A[m = lane&15][k = kk*32 + (lane>>4)*8 + e]
    bf16x8 Ah[4][6], Al[4][6];
    #pragma unroll
    for (int cls = 0; cls < 4; ++cls) {
        const int g = 128 * cls + 16 * wv + n;   // weight row for this lane's A m-row
        #pragma unroll
        for (int kk = 0; kk < 6; ++kk) {
            const int cb = kk * 32 + qrt * 8;    // 8 cols, never straddles x/h split
            const float* src = (cb < ISZ) ? (W_ih + (size_t)g * ISZ + cb)
                                          : (W_hh + (size_t)g * HSZ + (cb - ISZ));
            #pragma unroll
            for (int e = 0; e < 8; ++e) {
                float f = src[e];
                unsigned short hi = bf16_rn(f);
                Ah[cls][kk][e] = (short)hi;
                Al[cls][kk][e] = (short)bf16_rn(f - bf16_f(hi));
            }
        }
    }
    float bias[4][4];   // [cls][r] for gate 128*cls + u0 + r (C layout gates)
    #pragma unroll
    for (int cls = 0; cls < 4; ++cls)
        #pragma unroll
        for (int r = 0; r < 4; ++r) {
            const int g = 128 * cls + u0 + r;
            bias[cls][r] = b_ih[g] + b_hh[g];
        }
    float cst[4] = {0.f, 0.f, 0.f, 0.f};   // c-state of (u0+r, row n)

    // ---- init buf0: h(-1)=0, x(0) as bf16 hi/lo ----
    const int xrow = tid >> 5;          // 16 rows x 32 threads
    const int xi2  = (tid & 31) * 2;    // 2 x-values per thread
    {
        const int u4 = (tid & 31) * 4;
        *(unsigned long long*)&zH[0][xrow][ISZ + u4] = 0ull;
        *(unsigned long long*)&zL[0][xrow][ISZ + u4] = 0ull;
        const float* xp = x + ((size_t)(b0 + xrow) * T_STEPS) * ISZ + xi2;
        float f0 = xp[0], f1 = xp[1];
        unsigned short h0 = bf16_rn(f0), h1 = bf16_rn(f1);
        unsigned short l0 = bf16_rn(f0 - bf16_f(h0)), l1 = bf16_rn(f1 - bf16_f(h1));
        *(unsigned*)&zH[0][xrow][xi2] = (unsigned)h0 | ((unsigned)h1 << 16);
        *(unsigned*)&zL[0][xrow][xi2] = (unsigned)l0 | ((unsigned)l1 << 16);
    }
    __syncthreads();

    for (int t = 0; t < T_STEPS; ++t) {
        const int p = t & 1, q = p ^ 1;

        // x(t+1) prefetch: issue global load early, store after update
        float xf0 = 0.f, xf1 = 0.f;
        const bool pfv = (t + 1 < T_STEPS);
        if (pfv) {
            const float* xp = x + ((size_t)(b0 + xrow) * T_STEPS + (t + 1)) * ISZ + xi2;
            xf0 = xp[0]; xf1 = xp[1];
        }

        // ---- MFMA phase: C[cls] = W[cls-tiles] @ z  (bf16x3) ----
        f32x4 C[4];
        #pragma unroll
        for (int cls = 0; cls < 4; ++cls) C[cls] = (f32x4){0.f, 0.f, 0.f, 0.f};
        #pragma unroll
        for (int kk = 0; kk < 6; ++kk) {
            bf16x8 bh = *(const bf16x8*)&zH[p][n][kk * 32 + qrt * 8];
            bf16x8 bl = *(const bf16x8*)&zL[p][n][kk * 32 + qrt * 8];
            #pragma unroll
            for (int cls = 0; cls < 4; ++cls) {
                C[cls] = __builtin_amdgcn_mfma_f32_16x16x32_bf16(Ah[cls][kk], bh, C[cls], 0, 0, 0);
                C[cls] = __builtin_amdgcn_mfma_f32_16x16x32_bf16(Ah[cls][kk], bl, C[cls], 0, 0, 0);
                C[cls] = __builtin_amdgcn_mfma_f32_16x16x32_bf16(Al[cls][kk], bh, C[cls], 0, 0, 0);
            }
        }

        // ---- lane-local c/h update: 4 units x 1 row, all classes in-lane ----
        unsigned long long hHp = 0ull, hLp = 0ull;
        #pragma unroll
        for (int r = 0; r < 4; ++r) {
            float ig = sigm (C[0][r] + bias[0][r]);
            float fg = sigm (C[1][r] + bias[1][r]);
            float gg = tanh_(C[2][r] + bias[2][r]);
            float og = sigm (C[3][r] + bias[3][r]);
            cst[r] = fmaf(fg, cst[r], ig * gg);
            float hval = og * tanh_(cst[r]);
            unsigned short hh = bf16_rn(hval);
            unsigned short hl = bf16_rn(hval - bf16_f(hh));
            hHp |= ((unsigned long long)hh) << (16 * r);
            hLp |= ((unsigned long long)hl) << (16 * r);
            if (t == T_STEPS - 1) hbuf[n][u0 + r] = hval;
        }
        *(unsigned long long*)&zH[q][n][ISZ + u0] = hHp;   // 4 consecutive units: b64
        *(unsigned long long*)&zL[q][n][ISZ + u0] = hLp;

        // x(t+1) store (disjoint LDS region from h writes)
        if (pfv) {
            unsigned short h0 = bf16_rn(xf0), h1 = bf16_rn(xf1);
            unsigned short l0 = bf16_rn(xf0 - bf16_f(h0)), l1 = bf16_rn(xf1 - bf16_f(h1));
            *(unsigned*)&zH[q][xrow][xi2] = (unsigned)h0 | ((unsigned)h1 << 16);
            *(unsigned*)&zL[q][xrow][xi2] = (unsigned)l0 | ((unsigned)l1 << 16);
        }
        __syncthreads();   // buf q complete: h(t) + x(t+1)
    }

    // ---- FC head: out[b] = W2 . (W1 h + b1) + b2, h fp32 from hbuf ----
    {
        const int m    = tid & 255;    // fc1 unit
        const int half = tid >> 8;     // rows half*8 .. half*8+7
        float acc[8];
        #pragma unroll
        for (int rr = 0; rr < 8; ++rr) acc[rr] = b1[m];
        const float4* w1r = (const float4*)(W1 + (size_t)m * HSZ);
        #pragma unroll 4
        for (int kc = 0; kc < 32; ++kc) {
            float4 w = w1r[kc];
            #pragma unroll
            for (int rr = 0; rr < 8; ++rr) {
                float4 h4 = *(const float4*)&hbuf[half * 8 + rr][kc * 4];
                acc[rr] = fmaf(w.x, h4.x, acc[rr]);
                acc[rr] = fmaf(w.y, h4.y, acc[rr]);
                acc[rr] = fmaf(w.z, h4.z, acc[rr]);
                acc[rr] = fmaf(w.w, h4.w, acc[rr]);
            }
        }
        const float w2 = W2[m];
        #pragma unroll
        for (int rr = 0; rr < 8; ++rr) {
            float v = acc[rr] * w2;
            #pragma unroll
            for (int off = 32; off >= 1; off >>= 1)
                v += __shfl_down(v, off, 64);
            if (lane == 0) red[half * 8 + rr][wv & 3] = v;
        }
    }
    __syncthreads();
    if (tid < ROWS)
        out[b0 + tid] = red[tid][0] + red[tid][1] + red[tid][2] + red[tid][3] + b2[0];
}

extern "C" void kernel_launch(void* const* d_in, const int* in_sizes, int n_in,
                              void* d_out, int out_size, void* d_ws, size_t ws_size,
                              hipStream_t stream) {
    const float* x    = (const float*)d_in[0];
    const float* W_ih = (const float*)d_in[1];
    const float* W_hh = (const float*)d_in[2];
    const float* b_ih = (const float*)d_in[3];
    const float* b_hh = (const float*)d_in[4];
    const float* W1   = (const float*)d_in[5];
    const float* b1   = (const float*)d_in[6];
    const float* W2   = (const float*)d_in[7];
    const float* b2   = (const float*)d_in[8];
    float* out = (float*)d_out;

    lstm_fused_kernel<<<dim3(NBLK), dim3(NTH), 0, stream>>>(
        x, W_ih, W_hh, b_ih, b_hh, W1, b1, W2, b2, out);
}